// Round 4
// baseline (461.032 us; speedup 1.0000x reference)
//
#include <hip/hip_runtime.h>
#include <stdint.h>

#define S_DIM 4096
#define K_TOP 64
#define THREADS 256
#define EPT 16           // elements per thread = 4096/256
#define CAND_CAP 256

// zbuf layout: int32 [B][S_DIM][K_TOP] ; 1 => masked (output 0), 0 => keep (output 1)

__global__ __launch_bounds__(256) void clear_zbuf_kernel(int4* __restrict__ zbuf4) {
    // 4*4096*64 ints = 65536 int4s ; grid 256x256 = 65536 threads
    zbuf4[blockIdx.x * blockDim.x + threadIdx.x] = make_int4(0, 0, 0, 0);
}

__device__ __forceinline__ unsigned long long shfl_xor_u64(unsigned long long v, int m) {
    uint32_t lo = (uint32_t)v, hi = (uint32_t)(v >> 32);
    lo = __shfl_xor(lo, m, 64);
    hi = __shfl_xor(hi, m, 64);
    return ((unsigned long long)hi << 32) | lo;
}

__global__ __launch_bounds__(256) void topk_kernel(const float* __restrict__ scores,
                                                   int* __restrict__ zbuf) {
    const int row  = blockIdx.x;          // b*S + s
    const int t    = threadIdx.x;
    const int lane = t & 63;
    const int wid  = t >> 6;

    __shared__ uint32_t sh_w16[4];
    __shared__ unsigned long long cand[CAND_CAP];
    __shared__ uint32_t sh_count;
    __shared__ unsigned long long sh_wbest[4];
    __shared__ unsigned long long sh_best;

    // ---- load 16 floats per thread, coalesced float4; monotonic u32 keys ----
    const float4* rowp = (const float4*)(scores + (size_t)row * S_DIM);
    uint32_t key[EPT];
    #pragma unroll
    for (int i = 0; i < 4; ++i) {
        float4 v = rowp[i * THREADS + t];
        float f[4] = {v.x, v.y, v.z, v.w};
        #pragma unroll
        for (int c = 0; c < 4; ++c) {
            uint32_t ub = __float_as_uint(f[c]);
            key[i * 4 + c] = (ub & 0x80000000u) ? ~ub : (ub | 0x80000000u);
        }
    }

    if (t == 0) sh_count = 0u;

    // ---- per-thread max of 16 keys ----
    uint32_t mx = key[0];
    #pragma unroll
    for (int i = 1; i < EPT; ++i) mx = max(mx, key[i]);

    // ---- wave-level bitonic sort (ascending by lane) of the 64 lane-maxes ----
    uint32_t x = mx;
    #pragma unroll
    for (int k = 2; k <= 64; k <<= 1) {
        #pragma unroll
        for (int j = k >> 1; j > 0; j >>= 1) {
            uint32_t v = __shfl_xor(x, j, 64);
            bool keepMin = (((lane & j) == 0) == ((lane & k) == 0));
            x = keepMin ? min(x, v) : max(x, v);
        }
    }
    // 16th-largest lane-max sits at lane 48 of the ascending sort
    uint32_t w16 = __shfl(x, 48, 64);
    if (lane == 0) sh_w16[wid] = w16;
    __syncthreads();                                    // barrier 1

    // Tc = min over waves: each wave has >=16 lane-maxes >= its w16, so >=64
    // elements >= Tc exist => Tc <= T(64th). {key >= Tc} superset of top-64.
    const uint32_t Tc = min(min(sh_w16[0], sh_w16[1]), min(sh_w16[2], sh_w16[3]));

    // ---- collect candidates ----
    #pragma unroll
    for (int i = 0; i < EPT; ++i) {
        if (key[i] >= Tc) {
            uint32_t idx = (((uint32_t)(i >> 2) * THREADS + (uint32_t)t) << 2) | (uint32_t)(i & 3);
            uint32_t pos = atomicAdd(&sh_count, 1u);
            if (pos < CAND_CAP) {
                // 64-bit composite: value desc primary, index asc secondary (all distinct)
                cand[pos] = ((unsigned long long)key[i] << 32) | (uint32_t)(~idx);
            }
        }
    }
    __syncthreads();                                    // barrier 2
    const uint32_t m = sh_count;

    const size_t zrow_base = (size_t)row * K_TOP;       // zbuf[b][s? no: b][idx][:] base via idx below

    if (m <= CAND_CAP) {                                // block-uniform branch
        if ((uint32_t)t < m) {
            unsigned long long me = cand[t];
            uint32_t rank = 0;
            for (uint32_t i = 0; i < m; ++i) rank += (cand[i] > me) ? 1u : 0u;
            if (rank < K_TOP) {
                uint32_t idx = ~(uint32_t)me;
                const int b = row >> 12;
                zbuf[((size_t)((b << 12) | (int)idx)) * K_TOP + rank] = 1;
            }
        }
        return;
    }

    // ---- fallback (adversarial ties only): exact 64-round argmax extraction ----
    (void)zrow_base;
    uint32_t used = 0u;
    for (int r = 0; r < K_TOP; ++r) {
        unsigned long long best = 0ull;
        #pragma unroll
        for (int i = 0; i < EPT; ++i) {
            if (!(used & (1u << i))) {
                uint32_t idx = (((uint32_t)(i >> 2) * THREADS + (uint32_t)t) << 2) | (uint32_t)(i & 3);
                unsigned long long ck = ((unsigned long long)key[i] << 32) | (uint32_t)(~idx);
                if (ck > best) best = ck;
            }
        }
        #pragma unroll
        for (int off = 32; off > 0; off >>= 1) {
            unsigned long long o = shfl_xor_u64(best, off);
            if (o > best) best = o;
        }
        if (lane == 0) sh_wbest[wid] = best;
        __syncthreads();
        if (t == 0) {
            unsigned long long bb = sh_wbest[0];
            for (int w = 1; w < 4; ++w) if (sh_wbest[w] > bb) bb = sh_wbest[w];
            sh_best = bb;
        }
        __syncthreads();
        const unsigned long long gb = sh_best;
        #pragma unroll
        for (int i = 0; i < EPT; ++i) {
            uint32_t idx = (((uint32_t)(i >> 2) * THREADS + (uint32_t)t) << 2) | (uint32_t)(i & 3);
            unsigned long long ck = ((unsigned long long)key[i] << 32) | (uint32_t)(~idx);
            if (ck == gb) {
                used |= (1u << i);
                uint32_t oidx = ~(uint32_t)gb;
                const int b = row >> 12;
                zbuf[((size_t)((b << 12) | (int)oidx)) * K_TOP + r] = 1;
            }
        }
        __syncthreads();
    }
}

__global__ __launch_bounds__(256) void fill_merge_kernel(int4* __restrict__ out4,
                                                         const int4* __restrict__ zbuf4,
                                                         int n4) {
    const int stride = gridDim.x * blockDim.x;
    const int4 ones = make_int4(1, 1, 1, 1);
    for (int f = blockIdx.x * blockDim.x + threadIdx.x; f < n4; f += stride) {
        const int c4 = f & 1023;            // int4-column within a 4096-wide row
        if (c4 >= K_TOP / 4) {
            out4[f] = ones;
        } else {
            const int r = (f >> 10) & (S_DIM - 1);
            const int b = f >> 22;
            const int4 z = zbuf4[(size_t)(((b << 12) | r) << 4) + c4];
            int4 v;
            v.x = z.x ? 0 : 1;
            v.y = z.y ? 0 : 1;
            v.z = z.z ? 0 : 1;
            v.w = z.w ? 0 : 1;
            if (r <= K_TOP) {               // triangle: rows <= 64, cols > r forced True
                const int c0 = c4 << 2;
                if (c0 + 0 > r) v.x = 1;
                if (c0 + 1 > r) v.y = 1;
                if (c0 + 2 > r) v.z = 1;
                if (c0 + 3 > r) v.w = 1;
            }
            out4[f] = v;
        }
    }
}

extern "C" void kernel_launch(void* const* d_in, const int* in_sizes, int n_in,
                              void* d_out, int out_size, void* d_ws, size_t ws_size,
                              hipStream_t stream) {
    const float* scores = (const float*)d_in[0];
    int* out = (int*)d_out;
    int* zbuf = (int*)d_ws;                       // B*S*K ints = 4 MB

    const int B = in_sizes[0] / (S_DIM * S_DIM);  // 4

    // 1) clear zbuf (B*S*K/4 int4s)
    const int z4 = B * S_DIM * K_TOP / 4;         // 65536
    hipLaunchKernelGGL(clear_zbuf_kernel, dim3(z4 / THREADS), dim3(THREADS), 0, stream,
                       (int4*)zbuf);

    // 2) top-k per row -> scatter 1s into compact zbuf
    hipLaunchKernelGGL(topk_kernel, dim3(B * S_DIM), dim3(THREADS), 0, stream,
                       scores, zbuf);

    // 3) dense output write, merging zbuf + triangle
    const int n4 = out_size / 4;                  // 16777216
    hipLaunchKernelGGL(fill_merge_kernel, dim3(8192), dim3(THREADS), 0, stream,
                       (int4*)out, (const int4*)zbuf, n4);
}